// Round 1
// baseline (12626.558 us; speedup 1.0000x reference)
//
#include <hip/hip_runtime.h>
#include <cstdint>
#include <cstddef>

// ---------------------------------------------------------------------------
// FieldLstmEncoder on MI355X (gfx950)
// B=128, S=512, UNI=512, HID=1024, FLD=128
// per step: pre[B,4096] = [x_t, h] @ W1^T + b1 ; rd[B,2048] = f_t @ W2^T + b2
//           c = sig(f+1)*c + sig(i)*tanh(j) + sig(r)*tanh(d); h = sig(o)*tanh(c)
// Strategy: bf16 MFMA (16x16x32), one fused kernel per timestep (kernel
// boundary = global sync), h double-buffered in ws, length-based early-out.
// ---------------------------------------------------------------------------

typedef __bf16 bf16;
typedef __bf16 bf16x8 __attribute__((ext_vector_type(8)));
typedef float floatx4 __attribute__((ext_vector_type(4)));

#define B_ 128
#define S_ 512
#define UNI_ 512
#define HID_ 1024
#define FLD_ 128
#define K1_ 1536   // UNI + HID
#define G4_ 4096   // 4*HID
#define G2_ 2048   // 2*HID

__device__ __forceinline__ float sigf(float x) { return 1.0f / (1.0f + __expf(-x)); }

// ---------------------------------------------------------------------------
// init: W1,W2 fp32 -> bf16 in ws; zero h (both buffers), c, h_f32; lenmax per
// 32-row group for early-out.
// ---------------------------------------------------------------------------
__global__ __launch_bounds__(256) void init_kernel(
    const float* __restrict__ W1, const float* __restrict__ W2,
    const int* __restrict__ len,
    bf16* __restrict__ W1b, bf16* __restrict__ W2b,
    bf16* __restrict__ h0, bf16* __restrict__ h1,
    float* __restrict__ c, float* __restrict__ hf,
    int* __restrict__ lenmax) {
  int i = blockIdx.x * 256 + threadIdx.x;
  if (i < G4_ * K1_) W1b[i] = (bf16)W1[i];
  if (i < G2_ * FLD_) W2b[i] = (bf16)W2[i];
  if (i < B_ * HID_) {
    h0[i] = (bf16)0.0f;
    h1[i] = (bf16)0.0f;
    c[i] = 0.0f;
    hf[i] = 0.0f;
  }
  if (i < 4) {
    int mx = 0;
    for (int b = 0; b < 32; ++b) {
      int l = len[i * 32 + b];
      mx = l > mx ? l : mx;
    }
    lenmax[i] = mx;
  }
}

// ---------------------------------------------------------------------------
// One timestep. Grid: 256 blocks of 256 threads.
//   nblk = bid & 63  -> 16 H-columns  [n0, n0+16)
//   mblk = bid >> 6  -> 32 batch rows [m0, m0+32)
// (4 row-blocks of a column tile are bids n, n+64, n+128, n+192 -> same
//  bid%8 -> same XCD under round-robin heuristic -> W1 column tile L2-shared)
// 4 waves: wave w -> mtile = w&1 (16 rows), gate pair gp = w>>1
//   gp=0: gates i(0),j(1) + rd gate r(0);  gp=1: gates f(2),o(3) + rd gate d(1)
// MFMA 16x16x32 bf16. A-frag: row m=lane&15, k=(lane>>4)*8+j (contiguous 8).
// B-frag: col n=lane&15, k=(lane>>4)*8+j -> W1 row-major [g][k] gives a direct
// 16B load per lane. C/D: col=lane&15, row=(lane>>4)*4+reg.
// ---------------------------------------------------------------------------
__global__ __launch_bounds__(256) void step_kernel(
    const float* __restrict__ x_all,   // [B][S][UNI] fp32
    const float* __restrict__ f_all,   // [B][S][FLD] fp32
    const int* __restrict__ len,       // [B]
    const float* __restrict__ b1,      // [4H]
    const float* __restrict__ b2,      // [2H]
    const bf16* __restrict__ W1b,      // [4H][K1] bf16
    const bf16* __restrict__ W2b,      // [2H][FLD] bf16
    const bf16* __restrict__ h_cur,    // [B][HID] bf16 (read)
    bf16* __restrict__ h_nxt,          // [B][HID] bf16 (write)
    float* __restrict__ c_ws,          // [B][HID] fp32 (rw, owner-exclusive)
    float* __restrict__ h_f32,         // [B][HID] fp32 (final h)
    const int* __restrict__ lenmax4,   // [4]
    float* __restrict__ out,           // d_out, outs part [B][S][HID]
    int t) {
  const int tid = threadIdx.x;
  const int bid = blockIdx.x;
  const int nblk = bid & 63;
  const int mblk = bid >> 6;
  const int n0 = nblk * 16;
  const int m0 = mblk * 32;

  // all 32 rows of this row-group finished: zero out, carry h forward.
  if (t >= lenmax4[mblk]) {
    for (int e = tid; e < 512; e += 256) {
      int bi = e >> 4, ni = e & 15;
      int b = m0 + bi, n = n0 + ni;
      out[(size_t)b * (S_ * HID_) + (size_t)t * HID_ + n] = 0.0f;
      h_nxt[b * HID_ + n] = h_cur[b * HID_ + n];
    }
    return;
  }

  __shared__ float pre_s[32][65];  // [row][gate*16 + ni], +1 pad vs conflicts
  __shared__ float rd_s[32][33];

  const int wave = tid >> 6;
  const int lane = tid & 63;
  const int quad = lane >> 4;
  const int l16 = lane & 15;
  const int mt = wave & 1;
  const int gp = wave >> 1;

  const int am = m0 + mt * 16 + l16;  // batch row this lane supplies for A
  const int kq = quad * 8;

  const float* xrow = x_all + ((size_t)am * S_ + t) * UNI_;
  const bf16* hrow = h_cur + (size_t)am * HID_;
  const bf16* w0 = W1b + (size_t)(gp * 2 * HID_ + n0 + l16) * K1_;
  const bf16* w1 = w0 + (size_t)HID_ * K1_;

  floatx4 acc0 = {0.0f, 0.0f, 0.0f, 0.0f};
  floatx4 acc1 = {0.0f, 0.0f, 0.0f, 0.0f};

  // ---- K in [0, UNI): A from x_t (fp32 -> bf16 on the fly) ----
#pragma unroll 4
  for (int kc = 0; kc < UNI_; kc += 32) {
    int k = kc + kq;
    const float4* q = (const float4*)(xrow + k);
    float4 u = q[0];
    float4 v = q[1];
    bf16x8 a;
    a[0] = (bf16)u.x; a[1] = (bf16)u.y; a[2] = (bf16)u.z; a[3] = (bf16)u.w;
    a[4] = (bf16)v.x; a[5] = (bf16)v.y; a[6] = (bf16)v.z; a[7] = (bf16)v.w;
    bf16x8 bA = *(const bf16x8*)(w0 + k);
    bf16x8 bB = *(const bf16x8*)(w1 + k);
    acc0 = __builtin_amdgcn_mfma_f32_16x16x32_bf16(a, bA, acc0, 0, 0, 0);
    acc1 = __builtin_amdgcn_mfma_f32_16x16x32_bf16(a, bB, acc1, 0, 0, 0);
  }

  // ---- K in [UNI, K1): A from h_prev (bf16 direct 16B loads) ----
#pragma unroll 4
  for (int kc = 0; kc < HID_; kc += 32) {
    int k = kc + kq;
    bf16x8 a = *(const bf16x8*)(hrow + k);
    bf16x8 bA = *(const bf16x8*)(w0 + UNI_ + k);
    bf16x8 bB = *(const bf16x8*)(w1 + UNI_ + k);
    acc0 = __builtin_amdgcn_mfma_f32_16x16x32_bf16(a, bA, acc0, 0, 0, 0);
    acc1 = __builtin_amdgcn_mfma_f32_16x16x32_bf16(a, bB, acc1, 0, 0, 0);
  }

  // ---- field GEMM: rd tile, K = FLD = 128 ----
  const float* frow = f_all + ((size_t)am * S_ + t) * FLD_;
  const bf16* w2 = W2b + (size_t)(gp * HID_ + n0 + l16) * FLD_;
  floatx4 accr = {0.0f, 0.0f, 0.0f, 0.0f};
#pragma unroll
  for (int kc = 0; kc < FLD_; kc += 32) {
    int k = kc + kq;
    const float4* q = (const float4*)(frow + k);
    float4 u = q[0];
    float4 v = q[1];
    bf16x8 a;
    a[0] = (bf16)u.x; a[1] = (bf16)u.y; a[2] = (bf16)u.z; a[3] = (bf16)u.w;
    a[4] = (bf16)v.x; a[5] = (bf16)v.y; a[6] = (bf16)v.z; a[7] = (bf16)v.w;
    bf16x8 bb = *(const bf16x8*)(w2 + k);
    accr = __builtin_amdgcn_mfma_f32_16x16x32_bf16(a, bb, accr, 0, 0, 0);
  }

  // ---- epilogue: fragments -> LDS ----
  {
    int row = mt * 16 + quad * 4;
#pragma unroll
    for (int r = 0; r < 4; ++r) {
      pre_s[row + r][(gp * 2) * 16 + l16] = acc0[r];
      pre_s[row + r][(gp * 2 + 1) * 16 + l16] = acc1[r];
      rd_s[row + r][gp * 16 + l16] = accr[r];
    }
  }
  __syncthreads();

  // ---- elementwise LSTM update: 512 (b,n) pairs, 2 per thread ----
  for (int e = tid; e < 512; e += 256) {
    int bi = e >> 4, ni = e & 15;
    int b = m0 + bi, n = n0 + ni;
    float iv = pre_s[bi][ni] + b1[n];
    float jv = pre_s[bi][16 + ni] + b1[HID_ + n];
    float fv = pre_s[bi][32 + ni] + b1[2 * HID_ + n];
    float ov = pre_s[bi][48 + ni] + b1[3 * HID_ + n];
    float rv = rd_s[bi][ni] + b2[n];
    float dv = rd_s[bi][16 + ni] + b2[HID_ + n];

    bool fin = (t >= len[b]);
    size_t cidx = (size_t)b * HID_ + n;
    float cp = c_ws[cidx];
    float cn = sigf(fv + 1.0f) * cp + sigf(iv) * tanhf(jv) + sigf(rv) * tanhf(dv);
    float hn = sigf(ov) * tanhf(cn);

    out[(size_t)b * (S_ * HID_) + (size_t)t * HID_ + n] = fin ? 0.0f : hn;
    if (fin) {
      h_nxt[cidx] = h_cur[cidx];  // carry frozen h across buffer swap
    } else {
      h_nxt[cidx] = (bf16)hn;
      c_ws[cidx] = cn;
      h_f32[cidx] = hn;
    }
  }
}

// ---------------------------------------------------------------------------
// finalize: write (h, c) tails of d_out
// ---------------------------------------------------------------------------
__global__ __launch_bounds__(256) void final_kernel(const float* __restrict__ hf,
                                                    const float* __restrict__ c,
                                                    float* __restrict__ out) {
  int i = blockIdx.x * 256 + threadIdx.x;  // 131072 total
  const size_t base = (size_t)B_ * S_ * HID_;
  out[base + i] = hf[i];
  out[base + (size_t)B_ * HID_ + i] = c[i];
}

// ---------------------------------------------------------------------------
extern "C" void kernel_launch(void* const* d_in, const int* in_sizes, int n_in,
                              void* d_out, int out_size, void* d_ws, size_t ws_size,
                              hipStream_t stream) {
  const float* x = (const float*)d_in[0];
  const float* f = (const float*)d_in[1];
  const int* len = (const int*)d_in[2];
  const float* W1 = (const float*)d_in[3];
  const float* b1 = (const float*)d_in[4];
  const float* W2 = (const float*)d_in[5];
  const float* b2 = (const float*)d_in[6];
  float* out = (float*)d_out;

  // workspace layout (bytes):
  char* ws = (char*)d_ws;
  bf16* W1b = (bf16*)(ws);                  // 4096*1536*2 = 12,582,912
  bf16* W2b = (bf16*)(ws + 12582912);       // 2048*128*2  =    524,288
  bf16* h0 = (bf16*)(ws + 13107200);        // 128*1024*2  =    262,144
  bf16* h1 = (bf16*)(ws + 13369344);        // 128*1024*2  =    262,144
  float* c = (float*)(ws + 13631488);       // 128*1024*4  =    524,288
  float* hf = (float*)(ws + 14155776);      // 128*1024*4  =    524,288
  int* lenmax = (int*)(ws + 14680064);      // 16
  // total ~14.7 MB

  init_kernel<<<(G4_ * K1_ + 255) / 256, 256, 0, stream>>>(
      W1, W2, len, W1b, W2b, h0, h1, c, hf, lenmax);

  for (int t = 0; t < S_; ++t) {
    const bf16* hc = (t & 1) ? h1 : h0;
    bf16* hn = (t & 1) ? h0 : h1;
    step_kernel<<<256, 256, 0, stream>>>(x, f, len, b1, b2, W1b, W2b, hc, hn, c,
                                         hf, lenmax, out, t);
  }

  final_kernel<<<512, 256, 0, stream>>>(hf, c, out);
}

// Round 2
// 7861.613 us; speedup vs baseline: 1.6061x; 1.6061x over previous
//
#include <hip/hip_runtime.h>
#include <cstdint>
#include <cstddef>

// ---------------------------------------------------------------------------
// FieldLstmEncoder on MI355X (gfx950)   B=128 S=512 UNI=512 HID=1024 FLD=128
// Step layout: 256 blocks x 512 thr (8 waves). Block nb owns H-cols
// [4nb,4nb+4) across ALL 4 gates and ALL 128 (length-sorted) batch rows.
// One MFMA N-dim (16) = 4 gates x 4 cols -> LSTM update is block-local.
// W1 slice (16 rows x 1536) staged in LDS per step; x,f pre-converted bf16.
// ---------------------------------------------------------------------------

typedef __bf16 bf16;
typedef __bf16 bf16x8 __attribute__((ext_vector_type(8)));
typedef float floatx4 __attribute__((ext_vector_type(4)));

#define B_ 128
#define S_ 512
#define UNI_ 512
#define HID_ 1024
#define FLD_ 128
#define K1_ 1536
#define BS_STRIDE 1544  // 1536 + 8 bf16 pad (16B) -> bank spread

__device__ __forceinline__ float sigf(float x) { return 1.0f / (1.0f + __expf(-x)); }

// ---------------------------------------------------------------------------
__global__ __launch_bounds__(128) void sort_kernel(const int* __restrict__ len,
                                                   int* __restrict__ perm,
                                                   int* __restrict__ lens) {
  int i = threadIdx.x;  // 128 threads, 1 block
  int li = len[i];
  int r = 0;
  for (int j = 0; j < B_; ++j) {
    int lj = len[j];
    r += (lj > li) || (lj == li && j < i) ? 1 : 0;
  }
  perm[r] = i;
  lens[r] = li;
}

__global__ __launch_bounds__(256) void conv_w(const float* __restrict__ W1,
                                              const float* __restrict__ W2,
                                              bf16* __restrict__ W1b,
                                              bf16* __restrict__ W2b) {
  int i = blockIdx.x * 256 + threadIdx.x;
  if (i < 4096 * K1_) W1b[i] = (bf16)W1[i];
  else {
    int j = i - 4096 * K1_;
    if (j < 2048 * FLD_) W2b[j] = (bf16)W2[j];
  }
}

__global__ __launch_bounds__(256) void zero_state(bf16* __restrict__ h0,
                                                  bf16* __restrict__ h1,
                                                  float* __restrict__ c,
                                                  float* __restrict__ hf) {
  int i = blockIdx.x * 256 + threadIdx.x;  // 131072
  h0[i] = (bf16)0.0f;
  h1[i] = (bf16)0.0f;
  c[i] = 0.0f;
  hf[i] = 0.0f;
}

// x,f fp32 -> bf16, rows permuted to sorted order. grid (S, B), 256 thr.
__global__ __launch_bounds__(256) void conv_xf(const float* __restrict__ x,
                                               const float* __restrict__ f,
                                               const int* __restrict__ perm,
                                               bf16* __restrict__ xbf,
                                               bf16* __restrict__ fbf) {
  int t = blockIdx.x, rs = blockIdx.y, tid = threadIdx.x;
  int b = perm[rs];
  const float* xs = x + ((size_t)b * S_ + t) * UNI_;
  bf16* xd = xbf + ((size_t)rs * S_ + t) * UNI_;
  xd[tid] = (bf16)xs[tid];
  xd[tid + 256] = (bf16)xs[tid + 256];
  if (tid < FLD_) {
    fbf[((size_t)rs * S_ + t) * FLD_ + tid] =
        (bf16)f[((size_t)b * S_ + t) * FLD_ + tid];
  }
}

// zero out[b][t][:] for t >= len[b]. grid (S, B), 256 thr x float4.
__global__ __launch_bounds__(256) void zero_tail(const int* __restrict__ len,
                                                 float* __restrict__ out) {
  int t = blockIdx.x, b = blockIdx.y;
  if (t < len[b]) return;
  float4 z = {0.0f, 0.0f, 0.0f, 0.0f};
  float4* o = (float4*)(out + ((size_t)b * S_ + t) * HID_);
  o[threadIdx.x] = z;
}

// ---------------------------------------------------------------------------
// One timestep.
// ---------------------------------------------------------------------------
__global__ __launch_bounds__(512, 2) void step_kernel(
    const bf16* __restrict__ xbf,     // [128][S][UNI] sorted rows
    const bf16* __restrict__ fbf,     // [128][S][FLD] sorted rows
    const bf16* __restrict__ W1b,     // [4H][K1]
    const bf16* __restrict__ W2b,     // [2H][FLD]
    const float* __restrict__ bias1,  // [4H]
    const float* __restrict__ bias2,  // [2H]
    const bf16* __restrict__ h_cur,   // [128][HID] sorted (read)
    bf16* __restrict__ h_nxt,         // [128][HID] sorted (write)
    float* __restrict__ c_ws,         // [128][HID] fp32 sorted
    float* __restrict__ hf,           // [128][HID] fp32 sorted
    const int* __restrict__ perm_g,   // [128] sorted -> orig
    const int* __restrict__ lens_g,   // [128] sorted desc
    float* __restrict__ out, int t) {
  __shared__ bf16 Bs[16 * BS_STRIDE];   // 49408 B
  __shared__ float pre_s[128][17];      // 8704 B
  __shared__ float rd_s[128][9];        // 4608 B
  __shared__ int lens_s[128];
  __shared__ int perm_s[128];

  const int tid = threadIdx.x;
  const int nb = blockIdx.x;
  const int c0 = nb * 4;

  // ---- stage W1 slice (16 gate-rows x 1536) into LDS ----
  {
    const int n = tid >> 5;  // 0..15
    const int s = tid & 31;
    const int wrow = (n >> 2) * HID_ + c0 + (n & 3);
    const bf16* src = W1b + (size_t)wrow * K1_;
    bf16* dst = Bs + n * BS_STRIDE;
#pragma unroll
    for (int p = 0; p < 6; ++p) {
      int off = (p * 32 + s) * 8;
      *(bf16x8*)(dst + off) = *(const bf16x8*)(src + off);
    }
  }
  if (tid < 128) {
    lens_s[tid] = lens_g[tid];
    perm_s[tid] = perm_g[tid];
  }
  __syncthreads();

  const int wave = tid >> 6;
  const int lane = tid & 63;
  const int quad = lane >> 4;
  const int l16 = lane & 15;
  const int m = wave * 16 + l16;  // A row (sorted batch index)
  const int kq = quad * 8;

  const bool wave_active = (t < lens_s[wave * 16]);  // lens sorted desc

  if (wave_active) {
    floatx4 acc_a = {0.f, 0.f, 0.f, 0.f};
    floatx4 acc_b = {0.f, 0.f, 0.f, 0.f};
    floatx4 accr = {0.f, 0.f, 0.f, 0.f};
    const bf16* xrow = xbf + ((size_t)m * S_ + t) * UNI_ + kq;
    const bf16* hrow = h_cur + (size_t)m * HID_ + kq;
    const bf16* bsl = Bs + l16 * BS_STRIDE + kq;

    // ---- K in [0,512): A = x_t (bf16 pre-converted) ----
#pragma unroll
    for (int kc = 0; kc < UNI_; kc += 64) {
      bf16x8 a0 = *(const bf16x8*)(xrow + kc);
      bf16x8 b0 = *(const bf16x8*)(bsl + kc);
      bf16x8 a1 = *(const bf16x8*)(xrow + kc + 32);
      bf16x8 b1 = *(const bf16x8*)(bsl + kc + 32);
      acc_a = __builtin_amdgcn_mfma_f32_16x16x32_bf16(a0, b0, acc_a, 0, 0, 0);
      acc_b = __builtin_amdgcn_mfma_f32_16x16x32_bf16(a1, b1, acc_b, 0, 0, 0);
    }
    // ---- K in [512,1536): A = h_prev ----
#pragma unroll 8
    for (int kc = 0; kc < HID_; kc += 64) {
      bf16x8 a0 = *(const bf16x8*)(hrow + kc);
      bf16x8 b0 = *(const bf16x8*)(bsl + UNI_ + kc);
      bf16x8 a1 = *(const bf16x8*)(hrow + kc + 32);
      bf16x8 b1 = *(const bf16x8*)(bsl + UNI_ + kc + 32);
      acc_a = __builtin_amdgcn_mfma_f32_16x16x32_bf16(a0, b0, acc_a, 0, 0, 0);
      acc_b = __builtin_amdgcn_mfma_f32_16x16x32_bf16(a1, b1, acc_b, 0, 0, 0);
    }
    // ---- field GEMM (K=128), B direct from global (tiny) ----
    {
      const bf16* frow = fbf + ((size_t)m * S_ + t) * FLD_ + kq;
      const int w2row = ((l16 >> 2) & 1) * HID_ + c0 + (l16 & 3);
      const bf16* w2p = W2b + (size_t)w2row * FLD_ + kq;
#pragma unroll
      for (int kc = 0; kc < FLD_; kc += 32) {
        bf16x8 a0 = *(const bf16x8*)(frow + kc);
        bf16x8 b0 = *(const bf16x8*)(w2p + kc);
        accr = __builtin_amdgcn_mfma_f32_16x16x32_bf16(a0, b0, accr, 0, 0, 0);
      }
    }
    // ---- acc -> LDS (C/D: col=l16, row=quad*4+r) ----
    const int row0 = wave * 16 + quad * 4;
#pragma unroll
    for (int r = 0; r < 4; ++r) {
      pre_s[row0 + r][l16] = acc_a[r] + acc_b[r];
      if (l16 < 8) rd_s[row0 + r][l16] = accr[r];
    }
  }
  __syncthreads();

  // ---- LSTM elementwise update: thread -> (row, col) ----
  {
    const int row = tid >> 2;
    const int cc = tid & 3;
    const int col = c0 + cc;
    const size_t sidx = (size_t)row * HID_ + col;
    if (t >= lens_s[row]) {
      h_nxt[sidx] = h_cur[sidx];  // frozen: carry across double-buffer
    } else {
      float iv = pre_s[row][cc] + bias1[col];
      float jv = pre_s[row][4 + cc] + bias1[HID_ + col];
      float fv = pre_s[row][8 + cc] + bias1[2 * HID_ + col];
      float ov = pre_s[row][12 + cc] + bias1[3 * HID_ + col];
      float rv = rd_s[row][cc] + bias2[col];
      float dv = rd_s[row][4 + cc] + bias2[HID_ + col];
      float cp = c_ws[sidx];
      float cn = sigf(fv + 1.0f) * cp + sigf(iv) * tanhf(jv) + sigf(rv) * tanhf(dv);
      float hn = sigf(ov) * tanhf(cn);
      out[(size_t)perm_s[row] * (S_ * HID_) + (size_t)t * HID_ + col] = hn;
      h_nxt[sidx] = (bf16)hn;
      c_ws[sidx] = cn;
      hf[sidx] = hn;
    }
  }
}

// ---------------------------------------------------------------------------
__global__ __launch_bounds__(256) void final_kernel(const float* __restrict__ hf,
                                                    const float* __restrict__ c,
                                                    const int* __restrict__ perm,
                                                    float* __restrict__ out) {
  int i = blockIdx.x * 256 + threadIdx.x;  // 131072
  int rs = i >> 10, n = i & 1023;
  int b = perm[rs];
  const size_t base = (size_t)B_ * S_ * HID_;
  out[base + (size_t)b * HID_ + n] = hf[i];
  out[base + (size_t)B_ * HID_ + (size_t)b * HID_ + n] = c[i];
}

// ---------------------------------------------------------------------------
extern "C" void kernel_launch(void* const* d_in, const int* in_sizes, int n_in,
                              void* d_out, int out_size, void* d_ws, size_t ws_size,
                              hipStream_t stream) {
  const float* x = (const float*)d_in[0];
  const float* f = (const float*)d_in[1];
  const int* len = (const int*)d_in[2];
  const float* W1 = (const float*)d_in[3];
  const float* b1 = (const float*)d_in[4];
  const float* W2 = (const float*)d_in[5];
  const float* b2 = (const float*)d_in[6];
  float* out = (float*)d_out;

  char* ws = (char*)d_ws;
  bf16* W1b = (bf16*)(ws);                    // 12,582,912
  bf16* W2b = (bf16*)(ws + 12582912);         //    524,288
  bf16* xbf = (bf16*)(ws + 13107200);         // 67,108,864
  bf16* fbf = (bf16*)(ws + 80216064);         // 16,777,216
  bf16* h0 = (bf16*)(ws + 96993280);          //    262,144
  bf16* h1 = (bf16*)(ws + 97255424);          //    262,144
  float* c = (float*)(ws + 97517568);         //    524,288
  float* hf = (float*)(ws + 98041856);        //    524,288
  int* perm = (int*)(ws + 98566144);          //        512
  int* lens = (int*)(ws + 98566656);          //        512
  // total ~98.6 MB

  sort_kernel<<<1, 128, 0, stream>>>(len, perm, lens);
  conv_w<<<(4096 * K1_ + 2048 * FLD_ + 255) / 256, 256, 0, stream>>>(W1, W2, W1b, W2b);
  zero_state<<<512, 256, 0, stream>>>(h0, h1, c, hf);
  conv_xf<<<dim3(S_, B_), 256, 0, stream>>>(x, f, perm, xbf, fbf);
  zero_tail<<<dim3(S_, B_), 256, 0, stream>>>(len, out);

  for (int t = 0; t < S_; ++t) {
    const bf16* hc = (t & 1) ? h1 : h0;
    bf16* hn = (t & 1) ? h0 : h1;
    step_kernel<<<256, 512, 0, stream>>>(xbf, fbf, W1b, W2b, b1, b2, hc, hn, c,
                                         hf, perm, lens, out, t);
  }

  final_kernel<<<512, 256, 0, stream>>>(hf, c, perm, out);
}